// Round 2
// baseline (76.888 us; speedup 1.0000x reference)
//
#include <hip/hip_runtime.h>

// Euler characteristic curve (ECC) of V-construction cubical complex.
// x: [64,3,224,224] fp32 in [0,1). Out: [64,96] fp32 = per-(b,c) ECC over
// tseq = linspace(0,1,32); out[img*32+t], img = b*3+c.
//
// Cell->bin: bin(f) = ceil(31*f); monotonic so bin(max) = max(bin).
// Net-update formulation (one histogram slot per pixel per family):
//   pair1 (vertex/h-edge) at pixel k, d_k = [B_{k+1}>B_k]:  @B_k: d_k - d_{k-1}
//   pair2 (v-edge/square) along M_k = max(B_k,C_k), e_k = [M_{k+1}>M_k]:
//                                                           @M_k: e_{k-1} - e_k
// Sentinels: RIGHT neighbor of col 223 -> bin 64 (always-true). LEFT neighbor
// of col 0 -> bin 63 (always >=). Bottom row (r==H-1) skips pair2.
// Math identical to R8/R9 (verified absmax=0); only the accumulation
// substrate changes.
//
// R10 (resubmit; R10 bench was an infra failure, no signal): kill LDS
// atomics. Theory: ds_add_u32 throughput ~1 lane/cyc/CU -> 19.3M
// lane-atomics = ~31 us = the whole kernel (matches measured 75.4 - 43.5
// fill). Lanes already hit distinct columns (addr = bin*64 + c, c=lane), so
// atomics only arbitrated the 4 waves sharing one slab. Now: per-wave
// PRIVATE slabs, plain read-modify-write (in-order per lane on the LDS pipe,
// bank pattern still c%32 = 2-way aliasing = free). To keep 6 blocks/CU
// (grid 1536 = 6*256 exact fit), slabs are packed: 2 bins per 32-bit word as
// biased 16-bit halves (17 words * 64 cols * 4 waves = 17408 B). Bias 64 per
// half: low-half updates add v directly (running value stays in [8,120] --
// per-bin per-family net is within +/-4 per row, 2 families, 7 rows ->
// +/-56 -- so no borrow/carry ever crosses the half boundary); high-half
// updates add v<<16 (mod-2^32 safe). Reduction extracts halves and
// subtracts the bias (256 halves/bin).

#define H 224
#define W 224
#define STEPS 32
#define NWORDS 17           // 33 bins packed 2/word; bin 32 (f==1.0) safe slot
#define NCOL 64
#define SLAB (NWORDS * NCOL)   // 1088 ints per wave slab
#define BANDS 8
#define BAND_ROWS 28        // rows per block
#define SUB_ROWS 7          // rows per wave (4 waves per block)
#define NTHR 256
#define BIASW 0x00400040    // bias 64 in each 16-bit half

__device__ __forceinline__ int bin_of(float f) {
    // ceil(31*f) for f in [0,1): fma then trunc. 0.99999994f = 1-2^-24.
    return (int)fmaf(f, 31.0f, 0.99999994f);
}

// Packed-halfword histogram add: word (bin>>1), half (bin&1), value v in
// {-1,0,1}. Low half: += v (bias prevents borrow into high half). High half:
// += v<<16 (wraps mod 2^32, low half untouched). Plain LDS RMW -- no atomic.
__device__ __forceinline__ void hist_add(int* __restrict__ lhw, int bin, int v) {
    lhw[(bin >> 1) << 6] += (v << ((bin & 1) << 4));
}

struct BinState {
    int B0, B1, B2, B3, Bn, Bp;
};

// pair1: net vertex/h-edge updates at the 4 own pixels.
__device__ __forceinline__ void pair1_update(int* __restrict__ lhw,
                                             const BinState& S)
{
    int dm = (S.B0 > S.Bp) ? 1 : 0;
    int d0 = (S.B1 > S.B0) ? 1 : 0;
    int d1 = (S.B2 > S.B1) ? 1 : 0;
    int d2 = (S.B3 > S.B2) ? 1 : 0;
    int d3 = (S.Bn > S.B3) ? 1 : 0;
    hist_add(lhw, S.B0, d0 - dm);
    hist_add(lhw, S.B1, d1 - d0);
    hist_add(lhw, S.B2, d2 - d1);
    hist_add(lhw, S.B3, d3 - d2);
}

// pair2: net v-edge/square updates along M = max(B, C); rolls S <- C bins.
__device__ __forceinline__ void pair2_update_roll(int* __restrict__ lhw,
                                                  BinState& S, float4 G,
                                                  bool lastc, bool firstc)
{
    int C0 = bin_of(G.x), C1 = bin_of(G.y), C2 = bin_of(G.z), C3 = bin_of(G.w);
    int t;
    t = __shfl_down(C0, 1); int Cn = lastc  ? 64 : t;
    t = __shfl_up  (C3, 1); int Cp = firstc ? 63 : t;

    int M0 = max(S.B0, C0), M1 = max(S.B1, C1),
        M2 = max(S.B2, C2), M3 = max(S.B3, C3);
    int Mn = max(S.Bn, Cn), Mp = max(S.Bp, Cp);
    int em = (M0 > Mp) ? 1 : 0;
    int e0 = (M1 > M0) ? 1 : 0;
    int e1 = (M2 > M1) ? 1 : 0;
    int e2 = (M3 > M2) ? 1 : 0;
    int e3 = (Mn > M3) ? 1 : 0;
    hist_add(lhw, M0, em - e0);
    hist_add(lhw, M1, e0 - e1);
    hist_add(lhw, M2, e1 - e2);
    hist_add(lhw, M3, e2 - e3);

    S.B0 = C0; S.B1 = C1; S.B2 = C2; S.B3 = C3; S.Bn = Cn; S.Bp = Cp;
}

__global__ __launch_bounds__(NTHR, 6) void ecc_fused_kernel(
        const float* __restrict__ x, float* __restrict__ out)
{
    // Per-wave private packed slabs: no atomics anywhere in the hot loop.
    // RMW addr word = s*1088 + (bin>>1)*64 + c: bank = c%32 -> 2-way (free).
    __shared__ int lh[4 * SLAB];     // 17408 B
    __shared__ int bins[STEPS];

    const int tid = threadIdx.x;
    for (int i = tid; i < 4 * SLAB; i += NTHR) lh[i] = BIASW;
    __syncthreads();

    const int band = blockIdx.x & (BANDS - 1);
    const int img  = blockIdx.x / BANDS;          // 0..191
    const float* __restrict__ p = x + (size_t)img * (H * W);

    const int c = tid & 63;      // column group: cols 4c..4c+3 (active c<56); c==lane
    const int s = tid >> 6;      // sub-band id == wave id (rows uniform per wave)

    if (c < 56) {
        const bool lastc  = (c == 55);
        const bool firstc = (c == 0);
        const int  r0 = band * BAND_ROWS + s * SUB_ROWS;
        int* __restrict__ lhw = lh + s * SLAB + c;   // private wave slab + own column

        const float* __restrict__ row = p + r0 * W + (c << 2);
        float4 F = *(const float4*)row;
        BinState S;
        S.B0 = bin_of(F.x); S.B1 = bin_of(F.y);
        S.B2 = bin_of(F.z); S.B3 = bin_of(F.w);
        int t;
        t = __shfl_down(S.B0, 1); S.Bn = lastc  ? 64 : t;  // right: always-greater
        t = __shfl_up  (S.B3, 1); S.Bp = firstc ? 63 : t;  // left: never-smaller

        if (r0 != H - SUB_ROWS) {
            // Interior wave: branch-free unrolled body, loads pipeline ahead (R9).
            #pragma unroll
            for (int k = 0; k < SUB_ROWS; ++k) {
                pair1_update(lhw, S);
                float4 G = *(const float4*)(row + W);
                pair2_update_roll(lhw, S, G, lastc, firstc);
                row += W;
            }
        } else {
            // The single boundary wave (band 7, sub-band 3): 6 full rows,
            // then pair1-only on the bottom row (r == H-1).
            #pragma unroll
            for (int k = 0; k < SUB_ROWS - 1; ++k) {
                pair1_update(lhw, S);
                float4 G = *(const float4*)(row + W);
                pair2_update_roll(lhw, S, G, lastc, firstc);
                row += W;
            }
            pair1_update(lhw, S);
        }
    }
    __syncthreads();

    // Reduce 4 slabs x 64 columns -> 32 bin sums. Thread (b,g): b = bin,
    // g = 8-lane group; extracts half (b&1) of word (b>>1) across g's 8
    // columns in each slab. 256 biased halves per bin -> subtract 64*256.
    const int b = tid >> 3;              // 0..31
    const int g = tid & 7;
    const int hsh = (b & 1) << 4;
    int sum = 0;
    #pragma unroll
    for (int s2 = 0; s2 < 4; ++s2) {
        const int4* rp = (const int4*)(lh + s2 * SLAB + ((b >> 1) << 6) + (g << 3));
        int4 u0 = rp[0], u1 = rp[1];
        sum += ((u0.x >> hsh) & 0xFFFF) + ((u0.y >> hsh) & 0xFFFF)
             + ((u0.z >> hsh) & 0xFFFF) + ((u0.w >> hsh) & 0xFFFF)
             + ((u1.x >> hsh) & 0xFFFF) + ((u1.y >> hsh) & 0xFFFF)
             + ((u1.z >> hsh) & 0xFFFF) + ((u1.w >> hsh) & 0xFFFF);
    }
    sum += __shfl_xor(sum, 1);
    sum += __shfl_xor(sum, 2);
    sum += __shfl_xor(sum, 4);
    if (g == 0) bins[b] = sum - 64 * 256;   // strip bias: 256 halves per bin
    __syncthreads();

    // Wave 0, lanes 0..31: inclusive prefix over bins, then one float
    // atomicAdd per bin into d_out (8 band blocks accumulate per image).
    if (tid < STEPS) {
        int v = bins[tid];
        #pragma unroll
        for (int off = 1; off < STEPS; off <<= 1) {
            int u = __shfl_up(v, off);
            if (tid >= off) v += u;
        }
        atomicAdd(&out[img * STEPS + tid], (float)v);
    }
}

extern "C" void kernel_launch(void* const* d_in, const int* in_sizes, int n_in,
                              void* d_out, int out_size, void* d_ws, size_t ws_size,
                              hipStream_t stream) {
    const float* x = (const float*)d_in[0];
    float* out = (float*)d_out;

    const int nimg = in_sizes[0] / (H * W);      // 192

    dim3 grid(nimg * BANDS);
    ecc_fused_kernel<<<grid, NTHR, 0, stream>>>(x, out);
}